// Round 3
// baseline (395.304 us; speedup 1.0000x reference)
//
#include <hip/hip_runtime.h>
#include <math.h>

typedef _Float16 f16;
typedef _Float16 f16x2 __attribute__((ext_vector_type(2)));
typedef _Float16 f16x8 __attribute__((ext_vector_type(8)));
typedef float f32x4 __attribute__((ext_vector_type(4)));

#define NB 16
#define SS 2048
#define DD 512

// async global->LDS, 16B per lane; LDS dst = wave-uniform base + lane*16
__device__ __forceinline__ void gl_lds16(const void* g, void* l) {
  __builtin_amdgcn_global_load_lds(
      (const __attribute__((address_space(1))) unsigned int*)g,
      (__attribute__((address_space(3))) unsigned int*)l, 16, 0, 0);
}

// pack two f32 -> f16x2 word
__device__ __forceinline__ int pk2(float a, float b) {
  f16x2 t = {(f16)a, (f16)b};
  return __builtin_bit_cast(int, t);
}

// ---------------- cast x (fp32) -> fp16, 8 elems/thread ----------------
__global__ __launch_bounds__(256) void cast_kernel(const float* __restrict__ x,
                                                   f16* __restrict__ o) {
  size_t i = (size_t)blockIdx.x * 256 + threadIdx.x;
  const float4* p = (const float4*)x + i * 2;
  float4 a = p[0], b = p[1];
  f16x8 v = {(f16)a.x, (f16)a.y, (f16)a.z, (f16)a.w,
             (f16)b.x, (f16)b.y, (f16)b.z, (f16)b.w};
  *((f16x8*)o + i) = v;
}

// ---------------- transpose 512x512 weights, fp32 -> fp16, z picks matrix ----
__global__ __launch_bounds__(256) void transpose_kernel(
    const float* __restrict__ W0, const float* __restrict__ W1,
    const float* __restrict__ W2, f16* __restrict__ T0, f16* __restrict__ T1,
    f16* __restrict__ T2) {
  const float* W = (blockIdx.z == 0) ? W0 : (blockIdx.z == 1) ? W1 : W2;
  f16* Wt = (blockIdx.z == 0) ? T0 : (blockIdx.z == 1) ? T1 : T2;
  __shared__ float t[32][33];
  int bx = blockIdx.x * 32, by = blockIdx.y * 32;
  int c = threadIdx.x & 31, r0 = threadIdx.x >> 5;
  for (int r = r0; r < 32; r += 8) t[r][c] = W[(size_t)(by + r) * DD + bx + c];
  __syncthreads();
  for (int r = r0; r < 32; r += 8) Wt[(size_t)(bx + r) * DD + by + c] = (f16)t[c][r];
}

// ---------------- fused QKV GEMM, R7: double-buffered, one launch ------------
// R6 post-mortem: each of the 3 GEMM launches issued tile-kt DMA then
// immediately barriered (vmcnt(0) drain) -> every K-iter ate a full load
// latency; ~85% stall, ~310 TF aggregate. R7:
//  - double-buffered LDS (2x16KB): prologue stages tile 0; loop issues kt+1,
//    computes kt, ONE barrier/iter (attn-proven pattern)
//  - all 3 GEMMs in one 3072-block launch (decode per block): no launch gaps,
//    12 blocks/CU of TLP (5 resident by LDS)
//  - bijective XCD swizzle (3072%8==0): contiguous logical range per XCD ->
//    A-panel + W-matrix L2 locality
// C[M][N] = A[M][K=512] * Bt[N][K=512]^T ; 128x128 tile, BK=32, 4 waves,
// 16x16x32_f16. Layouts m89-verified.
__global__ __launch_bounds__(256) void gemm3_kernel(
    const f16* __restrict__ xh, const f16* __restrict__ WqT,
    const f16* __restrict__ WkT, const f16* __restrict__ WvT,
    f16* __restrict__ Qh, f16* __restrict__ Kh, f16* __restrict__ Vth,
    const float* __restrict__ bq, const float* __restrict__ bk,
    const float* __restrict__ bv) {
  // XCD swizzle: hardware gives XCD x blocks with blockIdx.x % 8 == x;
  // relabel so each XCD owns a contiguous 384-wide logical range.
  const int wid = (blockIdx.x & 7) * 384 + (blockIdx.x >> 3);
  const f16* A;
  const f16* Bt;
  f16* C;
  const float* bias;
  int m0, n0, ldc, bias_row;
  float scale;
  if (wid < 2048) {  // Q (0..1023) / K (1024..2047): C[32768][512] = xh * W^T
    const bool isK = wid >= 1024;
    const int r = wid & 1023;
    A = xh;
    Bt = isK ? WkT : WqT;
    C = isK ? Kh : Qh;
    bias = isK ? bk : bq;
    m0 = (r >> 2) * 128;
    n0 = (r & 3) * 128;
    ldc = DD;
    bias_row = 0;
    scale = isK ? 1.0f : 0.125f;  // fold 1/sqrt(64) into Q
  } else {  // V^T per batch: C[512][2048] = WvT * xh_b^T
    const int v = wid - 2048;
    const int bz = v >> 6, xy = v & 63;
    A = WvT;
    Bt = xh + (size_t)bz * SS * DD;
    C = Vth + (size_t)bz * (size_t)DD * SS;
    bias = bv;
    m0 = ((xy >> 4) & 3) * 128;
    n0 = (xy & 15) * 128;
    ldc = SS;
    bias_row = 1;
    scale = 1.0f;
  }
  __shared__ f16 Ash[2][128 * 32];
  __shared__ f16 Bsh[2][128 * 32];
  const int tid = threadIdx.x, lane = tid & 63, wave = tid >> 6;
  const int wm = wave & 1, wn = wave >> 1;
  const int l15 = lane & 15, lq = lane >> 4;
  f32x4 acc[4][4] = {};
  const int srow = tid >> 2, part = tid & 3;
  const f16* gA = A + (size_t)(m0 + srow) * DD + part * 8;
  const f16* gB = Bt + (size_t)(n0 + srow) * DD + part * 8;
  auto stage = [&](int sb, int kt) {
    f16* lA = &Ash[sb][tid * 8];
    f16* lB = &Bsh[sb][tid * 8];
    gl_lds16(gA + kt * 32, lA);
    gl_lds16(gA + 64 * DD + kt * 32, lA + 2048);
    gl_lds16(gB + kt * 32, lB);
    gl_lds16(gB + 64 * DD + kt * 32, lB + 2048);
  };
  stage(0, 0);
  __syncthreads();
  for (int kt = 0; kt < 16; ++kt) {
    const int buf = kt & 1;
    if (kt < 15) stage(buf ^ 1, kt + 1);  // issue early; lands by the barrier
    f16x8 af[4], bf[4];
#pragma unroll
    for (int i = 0; i < 4; ++i)
      af[i] = *(const f16x8*)&Ash[buf][(64 * wm + 16 * i + l15) * 32 + lq * 8];
#pragma unroll
    for (int j = 0; j < 4; ++j)
      bf[j] = *(const f16x8*)&Bsh[buf][(64 * wn + 16 * j + l15) * 32 + lq * 8];
#pragma unroll
    for (int i = 0; i < 4; ++i)
#pragma unroll
      for (int j = 0; j < 4; ++j)
        acc[i][j] = __builtin_amdgcn_mfma_f32_16x16x32_f16(af[i], bf[j], acc[i][j], 0, 0, 0);
    __syncthreads();  // drains next-tile DMA; protects buf from next-iter overwrite
  }
#pragma unroll
  for (int i = 0; i < 4; ++i) {
    int rb = 64 * wm + 16 * i + lq * 4;
#pragma unroll
    for (int j = 0; j < 4; ++j) {
      int cc = n0 + 64 * wn + 16 * j + l15;
#pragma unroll
      for (int r = 0; r < 4; ++r) {
        int rr = m0 + rb + r;
        float bv = bias_row ? bias[rr] : bias[cc];
        C[(size_t)rr * ldc + cc] = (f16)((acc[i][j][r] + bv) * scale);
      }
    }
  }
}

// ---------------- flash attention, R6 (unchanged this round) ----------------
// Swapped-QK, P fully in-register; LDS pipe at ~94% of data-rate for this
// decomposition (K reads 256KB + V reads 256KB + DMA 64KB per iter/CU).
__global__ __launch_bounds__(512, 2) void attn_kernel(
    const f16* __restrict__ Q, const f16* __restrict__ K,
    const f16* __restrict__ Vt, float* __restrict__ out) {
  const int id = blockIdx.x;
  const int b = (id & 7) + ((id >> 7) << 3);  // XCD x gets batches {x, x+8}
  const int qt = (id >> 3) & 15;
  const int tid = threadIdx.x, lane = tid & 63, wave = tid >> 6;
  const int l15 = lane & 15, lq = lane >> 4;

  __shared__ __align__(16) f16 Kl[2][32][520];  // [key][d], 1040B rows
  __shared__ __align__(16) f16 Vl[2][512][32];  // [e][key], XOR-swizzled quarters

  const f16* qp = Q + ((size_t)(b * SS + qt * 128 + wave * 16 + l15)) * DD + lq * 8;
  f16x8 qf[16];
#pragma unroll
  for (int kk = 0; kk < 16; ++kk) qf[kk] = *(const f16x8*)(qp + kk * 32);

  const f16* Kb = K + (size_t)b * SS * DD;   // [key][d]
  const f16* Vb = Vt + (size_t)b * DD * SS;  // [e][s]

  const int sdata = (lane & 3) ^ ((lane >> 3) & 3);
  const int vrow = lane >> 2;
  const int vs_off = (lq ^ ((l15 >> 1) & 3)) * 8;

  f16x8 onef;
#pragma unroll
  for (int j = 0; j < 8; ++j) onef[j] = (f16)1.0f;

  auto stage = [&](int sb, int kb) {
#pragma unroll
    for (int rr = 0; rr < 4; ++rr) {
      int row = wave * 4 + rr;
      gl_lds16(Kb + ((size_t)(kb + row)) * DD + lane * 8, &Kl[sb][row][lane * 8]);
    }
#pragma unroll
    for (int i = 0; i < 4; ++i) {
      int e0 = wave * 64 + i * 16;
      gl_lds16(Vb + (size_t)(e0 + vrow) * SS + kb + sdata * 8,
               (f16*)&Vl[sb][e0][0] + lane * 8);
    }
  };

  stage(0, 0);
  __syncthreads();

  f32x4 acco[32] = {};
  f32x4 accl = {};
  float m = -1e30f;

  for (int it = 0; it < 64; ++it) {
    const int buf = it & 1;
    if (it < 63) stage(buf ^ 1, (it + 1) * 32);
    f32x4 sa0 = {}, sa1 = {};
#pragma unroll
    for (int kk = 0; kk < 16; ++kk) {
      f16x8 b0 = *(const f16x8*)&Kl[buf][l15][kk * 32 + lq * 8];
      f16x8 b1 = *(const f16x8*)&Kl[buf][16 + l15][kk * 32 + lq * 8];
      sa0 = __builtin_amdgcn_mfma_f32_16x16x32_f16(b0, qf[kk], sa0, 0, 0, 0);
      sa1 = __builtin_amdgcn_mfma_f32_16x16x32_f16(b1, qf[kk], sa1, 0, 0, 0);
    }
    float lm = fmaxf(fmaxf(fmaxf(sa0[0], sa0[1]), fmaxf(sa0[2], sa0[3])),
                     fmaxf(fmaxf(sa1[0], sa1[1]), fmaxf(sa1[2], sa1[3])));
    if (__any(lm > m + 8.0f)) {
      float mx = lm;
      mx = fmaxf(mx, __shfl_xor(mx, 16));
      mx = fmaxf(mx, __shfl_xor(mx, 32));
      float mn = fmaxf(m, mx);
      float al = __expf(m - mn);
      m = mn;
      float alr[4];
#pragma unroll
      for (int r = 0; r < 4; ++r) alr[r] = __shfl(al, 4 * lq + r);
#pragma unroll
      for (int t = 0; t < 32; ++t)
#pragma unroll
        for (int r = 0; r < 4; ++r) acco[t][r] *= alr[r];
#pragma unroll
      for (int r = 0; r < 4; ++r) accl[r] *= alr[r];
    }
    int A0 = pk2(__expf(sa0[0] - m), __expf(sa0[1] - m));
    int A1 = pk2(__expf(sa0[2] - m), __expf(sa0[3] - m));
    int B0 = pk2(__expf(sa1[0] - m), __expf(sa1[1] - m));
    int B1 = pk2(__expf(sa1[2] - m), __expf(sa1[3] - m));
    const bool low = (lq < 2);
    int s0 = low ? B0 : A0, s1 = low ? B1 : A1;
    int X0 = __shfl_xor(s0, 32), X1 = __shfl_xor(s1, 32);
    int Y0 = low ? A0 : B0, Y1 = low ? A1 : B1;
    const bool sx = (lq == 0) || (lq == 3);
    int t0 = sx ? X0 : Y0, t1 = sx ? X1 : Y1;
    int Z0 = __shfl_xor(t0, 16), Z1 = __shfl_xor(t1, 16);
    union PU { int i[4]; f16x8 v; } pu;
    pu.i[0] = (lq == 0) ? Y0 : ((lq == 2) ? X0 : Z0);
    pu.i[1] = (lq == 0) ? Y1 : ((lq == 2) ? X1 : Z1);
    pu.i[2] = (lq == 1) ? X0 : ((lq == 3) ? Y0 : Z0);
    pu.i[3] = (lq == 1) ? X1 : ((lq == 3) ? Y1 : Z1);
    f16x8 pa = pu.v;
    accl = __builtin_amdgcn_mfma_f32_16x16x32_f16(pa, onef, accl, 0, 0, 0);
#pragma unroll
    for (int nn = 0; nn < 32; ++nn) {
      f16x8 vf = *(const f16x8*)&Vl[buf][nn * 16 + l15][vs_off];
      acco[nn] = __builtin_amdgcn_mfma_f32_16x16x32_f16(pa, vf, acco[nn], 0, 0, 0);
    }
    __syncthreads();
  }
  float inv[4];
#pragma unroll
  for (int r = 0; r < 4; ++r) inv[r] = 1.0f / accl[r];
  const size_t ob = ((size_t)(b * SS + qt * 128 + wave * 16 + 4 * lq)) * DD + l15;
#pragma unroll
  for (int nn = 0; nn < 32; ++nn)
#pragma unroll
    for (int r = 0; r < 4; ++r)
      out[ob + (size_t)r * DD + nn * 16] = acco[nn][r] * inv[r];
}

extern "C" void kernel_launch(void* const* d_in, const int* in_sizes, int n_in,
                              void* d_out, int out_size, void* d_ws, size_t ws_size,
                              hipStream_t stream) {
  const float* x = (const float*)d_in[0];
  const float* Wq = (const float*)d_in[1];
  const float* bq = (const float*)d_in[2];
  const float* Wk = (const float*)d_in[3];
  const float* bk = (const float*)d_in[4];
  const float* Wv = (const float*)d_in[5];
  const float* bv = (const float*)d_in[6];
  float* out = (float*)d_out;
  f16* ws = (f16*)d_ws;
  const size_t NX = (size_t)NB * SS * DD;  // 16,777,216
  f16* xh = ws;
  f16* Qh = ws + NX;
  f16* Kh = ws + 2 * NX;
  f16* Vth = ws + 3 * NX;
  f16* WqT = ws + 4 * NX;
  f16* WkT = WqT + DD * DD;
  f16* WvT = WkT + DD * DD;

  cast_kernel<<<NX / 8 / 256, 256, 0, stream>>>(x, xh);
  transpose_kernel<<<dim3(16, 16, 3), 256, 0, stream>>>(Wq, Wk, Wv, WqT, WkT, WvT);
  gemm3_kernel<<<3072, 256, 0, stream>>>(xh, WqT, WkT, WvT, Qh, Kh, Vth, bq, bk, bv);
  attn_kernel<<<256, 512, 0, stream>>>(Qh, Kh, Vth, out);
}